// Round 6
// baseline (388.654 us; speedup 1.0000x reference)
//
#include <hip/hip_runtime.h>
#include <stdint.h>

#define N_NODES_C 20000
#define N_EDGES_C 320000
#define NUM_RELS_C 16
#define FEAT_C 256
#define BM 32   // dsts per block in fused kernel

typedef __bf16 bf16_t;
typedef __bf16 bf16x8 __attribute__((ext_vector_type(8)));
typedef __bf16 bf16x4 __attribute__((ext_vector_type(4)));
typedef float f32x4 __attribute__((ext_vector_type(4)));

// ---- h fp32 -> bf16 ----
__global__ void cvt_h_kernel(const float* __restrict__ h, bf16_t* __restrict__ hB) {
  int i = (blockIdx.x * blockDim.x + threadIdx.x) * 4;
  float4 v = *(const float4*)(h + i);
  bf16x4 o = { (bf16_t)v.x, (bf16_t)v.y, (bf16_t)v.z, (bf16_t)v.w };
  *(bf16x4*)(hB + i) = o;
}

// ---- W [r][in][out] fp32 -> Wt2 [out][r*256+in] bf16, LDS tile transpose ----
__global__ void cvt_w2_kernel(const float* __restrict__ W, bf16_t* __restrict__ Wt2) {
  __shared__ float t[32][33];
  int r = blockIdx.z, i0 = blockIdx.x << 5, o0 = blockIdx.y << 5;
  int a = threadIdx.x >> 5;
  int b = threadIdx.x & 31;
#pragma unroll
  for (int k = 0; k < 4; ++k) {
    int i = a + (k << 3);
    t[i][b] = W[(r << 16) + ((i0 + i) << 8) + o0 + b];
  }
  __syncthreads();
#pragma unroll
  for (int k = 0; k < 4; ++k) {
    int o = a + (k << 3);
    Wt2[((size_t)(o0 + o) << 12) + (r << 8) + i0 + b] = (bf16_t)t[b][o];
  }
}

// ---- hist over (dst,rel) keys ----
__global__ void hist2_kernel(const int* __restrict__ dst, const int* __restrict__ rel,
                             int* __restrict__ hist2) {
  int e = blockIdx.x * blockDim.x + threadIdx.x;
  if (e < N_EDGES_C) atomicAdd(&hist2[dst[e] * NUM_RELS_C + rel[e]], 1);
}

// ---- per-dst sum of 16 rel counts ----
__global__ void dsum_kernel(const int* __restrict__ hist2, int* __restrict__ dcnt) {
  int d = blockIdx.x * blockDim.x + threadIdx.x;
  if (d >= N_NODES_C) return;
  int s = 0;
#pragma unroll
  for (int r = 0; r < NUM_RELS_C; ++r) s += hist2[d * NUM_RELS_C + r];
  dcnt[d] = s;
}

// ---- single-block exclusive scan of dcnt -> dstart[20001] ----
__global__ void scan_dst_kernel(const int* __restrict__ dcnt, int* __restrict__ dstart) {
  __shared__ int part[256];
  const int CH = 79;
  int t = threadIdx.x;
  int base = t * CH;
  int sum = 0;
  for (int i = 0; i < CH; ++i) {
    int idx = base + i;
    if (idx < N_NODES_C) sum += dcnt[idx];
  }
  part[t] = sum;
  __syncthreads();
  if (t == 0) {
    int run = 0;
    for (int i = 0; i < 256; ++i) { int v = part[i]; part[i] = run; run += v; }
  }
  __syncthreads();
  int run = part[t];
  for (int i = 0; i < CH; ++i) {
    int idx = base + i;
    if (idx < N_NODES_C) {
      dstart[idx] = run;
      run += dcnt[idx];
    }
  }
  if (t == 0) dstart[N_NODES_C] = N_EDGES_C;
}

// ---- per-dst 16-entry prefix: rstart[d*16+r] + cursors ----
__global__ void prefixB_kernel(const int* __restrict__ hist2, const int* __restrict__ dstart,
                               int* __restrict__ rstart, int* __restrict__ rcur) {
  int d = blockIdx.x * blockDim.x + threadIdx.x;
  if (d >= N_NODES_C) return;
  int run = dstart[d];
#pragma unroll
  for (int r = 0; r < NUM_RELS_C; ++r) {
    int idx = d * NUM_RELS_C + r;
    rstart[idx] = run;
    rcur[idx] = run;
    run += hist2[idx];
  }
  if (d == 0) rstart[N_NODES_C * NUM_RELS_C] = N_EDGES_C;
}

// ---- bucket edges sorted by (dst,rel); pack (norm_bf16<<16 | src) in 4 B ----
__global__ void bucket2_kernel(const int* __restrict__ dst, const int* __restrict__ src,
                               const int* __restrict__ rel, const float* __restrict__ norm,
                               int* __restrict__ rcur, uint32_t* __restrict__ bkt) {
  int e = blockIdx.x * blockDim.x + threadIdx.x;
  if (e < N_EDGES_C) {
    int pos = atomicAdd(&rcur[dst[e] * NUM_RELS_C + rel[e]], 1);
    bf16_t nb = (bf16_t)norm[e];
    uint16_t nbits = __builtin_bit_cast(uint16_t, nb);
    bkt[pos] = (uint32_t)src[e] | ((uint32_t)nbits << 16);
  }
}

// ---- FUSED aggregate+GEMM: block = 32 dsts x full N=256. No G intermediate.
// Per rel r: build A-tile [32 x 256] bf16 in LDS from edge CSR (h gathers are
// cache-resident), then MFMA vs Wt2[r] read DIRECTLY from global (2 MB,
// L2-resident), accumulating out-tile in registers across all 16 rels.
// Producer overlap: A(r+1) built (latency-heavy) before GEMM(r) (MFMA-heavy)
// in the same iteration; one barrier per rel. A-tile XOR-swizzled
// (phys_chunk = chunk ^ row) -> frag ds_read_b128 is 2-way = free (m136). ----
__global__ __launch_bounds__(256) void fused_kernel(
    const bf16_t* __restrict__ hB, const bf16_t* __restrict__ Wt2,
    const int* __restrict__ rstart, const uint32_t* __restrict__ bkt,
    float* __restrict__ out) {
  __shared__ bf16_t Asm[2][BM * 256];   // 2 x 16 KB
  __shared__ int rsl[BM * NUM_RELS_C + 1];
  int tid = threadIdx.x;
  int d0 = blockIdx.x * BM;
  for (int i = tid; i < BM * NUM_RELS_C + 1; i += 256)
    rsl[i] = rstart[d0 * NUM_RELS_C + i];
  __syncthreads();

  int lane = tid & 63;
  int wave = tid >> 6;
  int lq = lane >> 4, lr = lane & 15;
  int wn = wave * 64;

  int half8 = lane & 1;        // 8B half within 16B chunk (A-build write)
  int lchunk = lane >> 1;      // logical 16B chunk 0..31 (A-build write)

  // B lane base: row (wn+lr) of Wt2, k-offset lq*8 (elements)
  const bf16_t* bbase = Wt2 + ((size_t)(wn + lr) << 12) + lq * 8;

  f32x4 acc[2][4] = {};

  auto buildA = [&](int r, int buf) {
    bf16_t* A = Asm[buf];
#pragma unroll
    for (int ii = 0; ii < 8; ++ii) {
      int dl = wave * 8 + ii;
      int p0 = rsl[dl * NUM_RELS_C + r];
      int p1 = rsl[dl * NUM_RELS_C + r + 1];
      f32x4 a = {0.f, 0.f, 0.f, 0.f};
      for (int p = p0; p < p1; ++p) {
        uint32_t wd = bkt[p];
        int s = wd & 0xFFFF;
        float nm = (float)__builtin_bit_cast(bf16_t, (uint16_t)(wd >> 16));
        bf16x4 v = *(const bf16x4*)(hB + ((size_t)s << 8) + (lane << 2));
        a[0] += nm * (float)v[0];
        a[1] += nm * (float)v[1];
        a[2] += nm * (float)v[2];
        a[3] += nm * (float)v[3];
      }
      bf16x4 o = {(bf16_t)a[0], (bf16_t)a[1], (bf16_t)a[2], (bf16_t)a[3]};
      int phys = lchunk ^ dl;   // dl < 32
      *(bf16x4*)(A + dl * 256 + phys * 8 + half8 * 4) = o;
    }
  };

  buildA(0, 0);
  __syncthreads();

  for (int r = 0; r < NUM_RELS_C; ++r) {
    if (r < NUM_RELS_C - 1) buildA(r + 1, (r + 1) & 1);

    const bf16_t* A = Asm[r & 1];
    const bf16_t* brel = bbase + (r << 8);
    bf16x8 bb[2][4];
#pragma unroll
    for (int nt = 0; nt < 4; ++nt)
      bb[0][nt] = *(const bf16x8*)(brel + ((size_t)nt << 16));

#pragma unroll
    for (int kk = 0; kk < 8; ++kk) {
      if (kk < 7) {
#pragma unroll
        for (int nt = 0; nt < 4; ++nt)
          bb[(kk + 1) & 1][nt] = *(const bf16x8*)(brel + ((size_t)nt << 16) + (kk + 1) * 32);
      }
      bf16x8 af[2];
#pragma unroll
      for (int mt = 0; mt < 2; ++mt) {
        int row = mt * 16 + lr;
        int phys = (kk * 4 + lq) ^ row;
        af[mt] = *(const bf16x8*)&A[row * 256 + phys * 8];
      }
#pragma unroll
      for (int mt = 0; mt < 2; ++mt)
#pragma unroll
        for (int nt = 0; nt < 4; ++nt)
          acc[mt][nt] = __builtin_amdgcn_mfma_f32_16x16x32_bf16(af[mt], bb[kk & 1][nt], acc[mt][nt], 0, 0, 0);
    }
    __syncthreads();
  }

  // Epilogue: C/D map col=lane&15, row=quad*4+reg. Direct fp32 stores.
#pragma unroll
  for (int mt = 0; mt < 2; ++mt) {
#pragma unroll
    for (int rg = 0; rg < 4; ++rg) {
      int row = d0 + mt * 16 + lq * 4 + rg;   // 625*32=20000 exact, no bounds
#pragma unroll
      for (int nt = 0; nt < 4; ++nt)
        out[((size_t)row << 8) + wn + nt * 16 + lr] = acc[mt][nt][rg];
    }
  }
}

extern "C" void kernel_launch(void* const* d_in, const int* in_sizes, int n_in,
                              void* d_out, int out_size, void* d_ws, size_t ws_size,
                              hipStream_t stream) {
  const float* h    = (const float*)d_in[0];
  const float* W    = (const float*)d_in[1];
  const float* norm = (const float*)d_in[2];
  const int*   src  = (const int*)d_in[3];
  const int*   dst  = (const int*)d_in[4];
  const int*   rel  = (const int*)d_in[5];
  float* out = (float*)d_out;

  char* ws = (char*)d_ws;
  bf16_t* hB    = (bf16_t*)ws;                   // 10,240,000 B
  bf16_t* Wt2   = (bf16_t*)(ws + 10240000);      //  2,097,152 B
  int* rstart   = (int*)(ws + 12337152);         //  1,280,004 B (320001 ints)
  uint32_t* bkt = (uint32_t*)(ws + 13617156);    //  1,280,000 B
  int* hist2    = (int*)(ws + 14897156);         //  1,280,000 B
  int* dcnt     = (int*)(ws + 16177156);         //     80,000 B
  int* dstart   = (int*)(ws + 16257156);         //     80,004 B
  int* rcur     = (int*)(ws + 16337160);         //  1,280,000 B -> end ~17.6 MB

  hipMemsetAsync(hist2, 0, 1280000, stream);
  cvt_h_kernel<<<5000, 256, 0, stream>>>(h, hB);
  cvt_w2_kernel<<<dim3(8, 8, NUM_RELS_C), 256, 0, stream>>>(W, Wt2);
  hist2_kernel<<<1250, 256, 0, stream>>>(dst, rel, hist2);
  dsum_kernel<<<79, 256, 0, stream>>>(hist2, dcnt);
  scan_dst_kernel<<<1, 256, 0, stream>>>(dcnt, dstart);
  prefixB_kernel<<<79, 256, 0, stream>>>(hist2, dstart, rstart, rcur);
  bucket2_kernel<<<1250, 256, 0, stream>>>(dst, src, rel, norm, rcur, bkt);
  fused_kernel<<<N_NODES_C / BM, 256, 0, stream>>>(hB, Wt2, rstart, bkt, out);
}

// Round 7
// 314.067 us; speedup vs baseline: 1.2375x; 1.2375x over previous
//
#include <hip/hip_runtime.h>
#include <stdint.h>

#define N_NODES_C 20000
#define N_EDGES_C 320000
#define NUM_RELS_C 16

typedef __bf16 bf16_t;
typedef __bf16 bf16x8 __attribute__((ext_vector_type(8)));
typedef __bf16 bf16x4 __attribute__((ext_vector_type(4)));
typedef __bf16 bf16x2 __attribute__((ext_vector_type(2)));
typedef float f32x4 __attribute__((ext_vector_type(4)));

// ---- W [r][in][out] fp32 -> Wt2 [out][r*256+in] bf16, LDS tile transpose ----
__global__ void cvt_w2_kernel(const float* __restrict__ W, bf16_t* __restrict__ Wt2) {
  __shared__ float t[32][33];
  int r = blockIdx.z, i0 = blockIdx.x << 5, o0 = blockIdx.y << 5;
  int a = threadIdx.x >> 5;
  int b = threadIdx.x & 31;
#pragma unroll
  for (int k = 0; k < 4; ++k) {
    int i = a + (k << 3);
    t[i][b] = W[(r << 16) + ((i0 + i) << 8) + o0 + b];
  }
  __syncthreads();
#pragma unroll
  for (int k = 0; k < 4; ++k) {
    int o = a + (k << 3);
    Wt2[((size_t)(o0 + o) << 12) + (r << 8) + i0 + b] = (bf16_t)t[b][o];
  }
}

// ---- dst histogram (counts land in dcur) ----
__global__ void hist_dst_kernel(const int* __restrict__ dst, int* __restrict__ dcur) {
  int e = blockIdx.x * blockDim.x + threadIdx.x;
  if (e < N_EDGES_C) atomicAdd(&dcur[dst[e]], 1);
}

// ---- single-block exclusive scan: dcur counts -> dstart starts; dcur = cursors ----
__global__ void scan_dst_kernel(int* __restrict__ dcur, int* __restrict__ dstart) {
  __shared__ int part[256];
  const int CH = 79;
  int t = threadIdx.x;
  int base = t * CH;
  int sum = 0;
  for (int i = 0; i < CH; ++i) {
    int idx = base + i;
    if (idx < N_NODES_C) sum += dcur[idx];
  }
  part[t] = sum;
  __syncthreads();
  if (t == 0) {
    int run = 0;
    for (int i = 0; i < 256; ++i) { int v = part[i]; part[i] = run; run += v; }
  }
  __syncthreads();
  int run = part[t];
  for (int i = 0; i < CH; ++i) {
    int idx = base + i;
    if (idx < N_NODES_C) {
      int c = dcur[idx];
      dstart[idx] = run;
      dcur[idx] = run;
      run += c;
    }
  }
  if (t == 0) dstart[N_NODES_C] = N_EDGES_C;
}

// ---- bucket edges by dst; payload = {src | rel<<16, norm fp32 bits} ----
__global__ void bucket_dst_kernel(const int* __restrict__ dst, const int* __restrict__ src,
                                  const int* __restrict__ rel, const float* __restrict__ norm,
                                  int* __restrict__ dcur, uint2* __restrict__ bkt) {
  int e = blockIdx.x * blockDim.x + threadIdx.x;
  if (e < N_EDGES_C) {
    int pos = atomicAdd(&dcur[dst[e]], 1);
    uint2 v;
    v.x = (uint32_t)src[e] | ((uint32_t)rel[e] << 16);
    v.y = __builtin_bit_cast(uint32_t, norm[e]);
    bkt[pos] = v;
  }
}

// ---- transform: Tb[r][node][perm-pos] = (h @ W[r]) bf16, BARRIER-FREE rel loop.
// Block = 128 nodes x 64 out-cols. A staged ONCE in LDS (fp32->bf16, one
// barrier); B held in registers per rel-half, double-buffered, read straight
// from L2-resident Wt2 (2 MB). Stores fire-and-forget. A-frag layout = R4's
// measured-0-conflict pattern ([k-sub][row][32elem], chunk = lq^((lr>>1)&3)).
// Store permutation: value for col (n0+wn2+nt*16+lr) at pos (n0+wn2+lr*2+nt),
// so one bf16x2 store covers both nt; aggregate de-permutes on final write. ----
__global__ __launch_bounds__(256) void transform_kernel(
    const float* __restrict__ h, const bf16_t* __restrict__ Wt2,
    bf16_t* __restrict__ Tb) {
  int m0 = blockIdx.x * 128;
  int n0 = blockIdx.y * 64;
  __shared__ bf16_t Alds[8 * 128 * 32];   // 64 KB

  int tid = threadIdx.x;
#pragma unroll
  for (int c = 0; c < 16; ++c) {
    int idx = c * 256 + tid;          // 16B-chunk 0..4095
    int sub = idx >> 9;               // k-group of 32 elems
    int row = (idx >> 2) & 127;
    int pq  = idx & 3;
    int phys = pq ^ ((row >> 1) & 3);
    int gr = m0 + row; if (gr > N_NODES_C - 1) gr = N_NODES_C - 1;
    const float* s = h + ((size_t)gr << 8) + sub * 32 + phys * 8;
    float4 f0 = *(const float4*)s;
    float4 f1 = *(const float4*)(s + 4);
    bf16x8 pk = { (bf16_t)f0.x, (bf16_t)f0.y, (bf16_t)f0.z, (bf16_t)f0.w,
                  (bf16_t)f1.x, (bf16_t)f1.y, (bf16_t)f1.z, (bf16_t)f1.w };
    *(bf16x8*)&Alds[idx * 8] = pk;
  }
  __syncthreads();   // the only barrier

  int lane = tid & 63;
  int wave = tid >> 6;
  int lq = lane >> 4, lr = lane & 15;
  int wm = (wave >> 1) * 64;
  int wn2 = (wave & 1) * 32;
  int cq8 = (lq ^ ((lr >> 1) & 3)) * 8;

  const bf16_t* brow0 = Wt2 + ((size_t)(n0 + wn2 + lr) << 12) + lq * 8;
  const bf16_t* brow1 = Wt2 + ((size_t)(n0 + wn2 + 16 + lr) << 12) + lq * 8;

  bf16x8 B0[2][4], B1[2][4];   // two buffers: [nt][kk2]

#define LOADB(dst, r_, hh_)                                                  \
  {                                                                          \
    int base_ = ((r_) << 8) + (hh_) * 128;                                   \
    _Pragma("unroll")                                                        \
    for (int k2 = 0; k2 < 4; ++k2) {                                         \
      dst[0][k2] = *(const bf16x8*)(brow0 + base_ + k2 * 32);                \
      dst[1][k2] = *(const bf16x8*)(brow1 + base_ + k2 * 32);                \
    }                                                                        \
  }

  f32x4 acc[4][2] = {};
  LOADB(B0, 0, 0)

#pragma unroll 1
  for (int r = 0; r < NUM_RELS_C; ++r) {
    // half 0: compute from B0, prefetch (r,1) into B1
    LOADB(B1, r, 1)
#pragma unroll
    for (int k2 = 0; k2 < 4; ++k2) {
      bf16x8 af[4];
#pragma unroll
      for (int mt = 0; mt < 4; ++mt)
        af[mt] = *(const bf16x8*)&Alds[k2 * 4096 + (wm + mt * 16 + lr) * 32 + cq8];
#pragma unroll
      for (int mt = 0; mt < 4; ++mt) {
        acc[mt][0] = __builtin_amdgcn_mfma_f32_16x16x32_bf16(af[mt], B0[0][k2], acc[mt][0], 0, 0, 0);
        acc[mt][1] = __builtin_amdgcn_mfma_f32_16x16x32_bf16(af[mt], B0[1][k2], acc[mt][1], 0, 0, 0);
      }
    }
    // half 1: compute from B1, prefetch (r+1,0) into B0
    int rn = (r + 1) & (NUM_RELS_C - 1);
    LOADB(B0, rn, 0)
#pragma unroll
    for (int k2 = 0; k2 < 4; ++k2) {
      bf16x8 af[4];
#pragma unroll
      for (int mt = 0; mt < 4; ++mt)
        af[mt] = *(const bf16x8*)&Alds[(4 + k2) * 4096 + (wm + mt * 16 + lr) * 32 + cq8];
#pragma unroll
      for (int mt = 0; mt < 4; ++mt) {
        acc[mt][0] = __builtin_amdgcn_mfma_f32_16x16x32_bf16(af[mt], B1[0][k2], acc[mt][0], 0, 0, 0);
        acc[mt][1] = __builtin_amdgcn_mfma_f32_16x16x32_bf16(af[mt], B1[1][k2], acc[mt][1], 0, 0, 0);
      }
    }
    // epilogue rel r: permuted bf16x2 stores, then re-zero acc
    bf16_t* tb = Tb + ((size_t)r * N_NODES_C) * 256;
#pragma unroll
    for (int mt = 0; mt < 4; ++mt) {
#pragma unroll
      for (int rg = 0; rg < 4; ++rg) {
        int row = m0 + wm + mt * 16 + lq * 4 + rg;
        if (row < N_NODES_C) {
          bf16x2 pk = { (bf16_t)acc[mt][0][rg], (bf16_t)acc[mt][1][rg] };
          *(bf16x2*)&tb[((size_t)row << 8) + n0 + wn2 + lr * 2] = pk;
        }
      }
      acc[mt][0] = (f32x4){0.f, 0.f, 0.f, 0.f};
      acc[mt][1] = (f32x4){0.f, 0.f, 0.f, 0.f};
    }
  }
#undef LOADB
}

// ---- aggregate: one wave per dst, 2-way unrolled independent Tb gathers.
// Lane reads Tb row bytes [8l,8l+8) = permuted positions 4l..4l+3. ----
__global__ __launch_bounds__(256) void aggregate_kernel(
    const bf16_t* __restrict__ Tb, const int* __restrict__ dstart,
    const uint2* __restrict__ bkt, float* __restrict__ out) {
  int d = blockIdx.x * 4 + (threadIdx.x >> 6);
  int lane = threadIdx.x & 63;
  int p0 = dstart[d], p1 = dstart[d + 1];
  int loffB = lane * 8;
  f32x4 a = {0.f, 0.f, 0.f, 0.f};
  int p = p0;
  for (; p + 1 < p1; p += 2) {
    uint2 e0 = bkt[p];
    uint2 e1 = bkt[p + 1];
    int s0 = e0.x & 0xFFFF, r0 = e0.x >> 16;
    int s1 = e1.x & 0xFFFF, r1 = e1.x >> 16;
    float n0 = __builtin_bit_cast(float, e0.y);
    float n1 = __builtin_bit_cast(float, e1.y);
    bf16x4 v0 = *(const bf16x4*)((const char*)Tb + (((size_t)(r0 * N_NODES_C + s0)) << 9) + loffB);
    bf16x4 v1 = *(const bf16x4*)((const char*)Tb + (((size_t)(r1 * N_NODES_C + s1)) << 9) + loffB);
    a[0] += n0 * (float)v0[0] + n1 * (float)v1[0];
    a[1] += n0 * (float)v0[1] + n1 * (float)v1[1];
    a[2] += n0 * (float)v0[2] + n1 * (float)v1[2];
    a[3] += n0 * (float)v0[3] + n1 * (float)v1[3];
  }
  if (p < p1) {
    uint2 e0 = bkt[p];
    int s0 = e0.x & 0xFFFF, r0 = e0.x >> 16;
    float n0 = __builtin_bit_cast(float, e0.y);
    bf16x4 v0 = *(const bf16x4*)((const char*)Tb + (((size_t)(r0 * N_NODES_C + s0)) << 9) + loffB);
    a[0] += n0 * (float)v0[0];
    a[1] += n0 * (float)v0[1];
    a[2] += n0 * (float)v0[2];
    a[3] += n0 * (float)v0[3];
  }
  // de-permute: pos 4l+j -> col; j: 0->+0, 1->+16, 2->+1, 3->+17
  int pp = lane * 4;
  int nb = pp & ~63;
  int local = pp & 63;
  int wn2 = local & 32;
  int b2 = (local & 31) >> 1;
  float* o = out + ((size_t)d << 8) + nb + wn2 + b2;
  o[0]  = a[0];
  o[16] = a[1];
  o[1]  = a[2];
  o[17] = a[3];
}

extern "C" void kernel_launch(void* const* d_in, const int* in_sizes, int n_in,
                              void* d_out, int out_size, void* d_ws, size_t ws_size,
                              hipStream_t stream) {
  const float* h    = (const float*)d_in[0];
  const float* W    = (const float*)d_in[1];
  const float* norm = (const float*)d_in[2];
  const int*   src  = (const int*)d_in[3];
  const int*   dst  = (const int*)d_in[4];
  const int*   rel  = (const int*)d_in[5];
  float* out = (float*)d_out;

  char* ws = (char*)d_ws;
  bf16_t* Tb   = (bf16_t*)ws;                     // 163,840,000 B
  bf16_t* Wt2  = (bf16_t*)(ws + 163840000);       //   2,097,152 B
  uint2* bkt   = (uint2*)(ws + 165937152);        //   2,560,000 B (8-aligned)
  int* dstart  = (int*)(ws + 168497152);          //      80,004 B
  int* dcur    = (int*)(ws + 168577156);          //      80,000 B -> end ~168.66 MB

  hipMemsetAsync(dcur, 0, N_NODES_C * sizeof(int), stream);
  cvt_w2_kernel<<<dim3(8, 8, NUM_RELS_C), 256, 0, stream>>>(W, Wt2);
  hist_dst_kernel<<<1250, 256, 0, stream>>>(dst, dcur);
  scan_dst_kernel<<<1, 256, 0, stream>>>(dcur, dstart);
  bucket_dst_kernel<<<1250, 256, 0, stream>>>(dst, src, rel, norm, dcur, bkt);
  transform_kernel<<<dim3(157, 4), 256, 0, stream>>>(h, Wt2, Tb);
  aggregate_kernel<<<5000, 256, 0, stream>>>(Tb, dstart, bkt, out);
}